// Round 1
// baseline (1422.943 us; speedup 1.0000x reference)
//
#include <hip/hip_runtime.h>

// Problem constants (from reference)
#define N_CELL 60000
#define N_GENE 4000
#define DIM    128
#define EPS_BN 1e-5f

// Workspace layout (floats):
//   msg   [N_CELL*DIM]   = 7,680,000   @ 0
//   cnt   [N_CELL]       =    60,000   @ 7,680,000
//   stats [512]          (sum[128], sumsq[128], mu[128], istd[128]) @ 7,740,000
//   ygene [N_GENE*DIM]   =   512,000   @ 7,740,512
// total 8,252,512 floats = ~33 MB (zeroed region = first 7,740,512 floats)
#define WS_MSG    0
#define WS_CNT    7680000
#define WS_STATS  7740000
#define WS_YGENE  7740512
#define WS_ZERO_FLOATS 7740512  // msg + cnt + stats(first 512 incl.)

// ---------------------------------------------------------------------------
// Kernel 1: y_gene = x_gene @ Wl   [4000 x 128] = [4000 x 128] @ [128 x 128]
// 8 rows per block, 128 threads (one col each).
// ---------------------------------------------------------------------------
__global__ __launch_bounds__(128) void ygene_gemm(
    const float* __restrict__ xg, const float* __restrict__ Wl,
    float* __restrict__ y) {
  const int j  = threadIdx.x;        // output column
  const int r0 = blockIdx.x * 8;     // first of 8 gene rows
  float acc[8] = {0.f, 0.f, 0.f, 0.f, 0.f, 0.f, 0.f, 0.f};
  for (int k = 0; k < DIM; ++k) {
    const float w = Wl[k * DIM + j];              // coalesced across threads
#pragma unroll
    for (int r = 0; r < 8; ++r)
      acc[r] += xg[(size_t)(r0 + r) * DIM + k] * w;  // wave-uniform (scalar) loads
  }
#pragma unroll
  for (int r = 0; r < 8; ++r)
    y[(size_t)(r0 + r) * DIM + j] = acc[r];
}

// ---------------------------------------------------------------------------
// Kernel 2: edge scatter.  One wave per edge; lane handles 2 floats.
//   msg[dst] += y_gene[src];  cnt[dst] += 1
// ---------------------------------------------------------------------------
__global__ __launch_bounds__(256) void scatter_edges(
    const int* __restrict__ src, const int* __restrict__ dst,
    const float* __restrict__ y, float* __restrict__ msg,
    float* __restrict__ cnt, int E) {
  const int lane   = threadIdx.x & 63;
  const int wave   = (blockIdx.x * blockDim.x + threadIdx.x) >> 6;
  const int nwaves = (gridDim.x * blockDim.x) >> 6;
  for (int e = wave; e < E; e += nwaves) {
    const int s = src[e];
    const int d = dst[e];
    const float2 v = *(const float2*)(y + (size_t)s * DIM + lane * 2);
    float* m = msg + (size_t)d * DIM + lane * 2;
    unsafeAtomicAdd(m,     v.x);
    unsafeAtomicAdd(m + 1, v.y);
    if (lane == 0) unsafeAtomicAdd(cnt + d, 1.0f);
  }
}

// ---------------------------------------------------------------------------
// Kernel 3: out_pre = x_cell @ Wr + msg * (1/max(cnt,1)) + bl
// Tile: 64 rows x 128 cols per block, 256 threads, BK=16 LDS staging.
// Thread (tr,tc) computes 8 rows x 4 cols.
// ---------------------------------------------------------------------------
__global__ __launch_bounds__(256) void main_gemm(
    const float* __restrict__ xc, const float* __restrict__ Wr,
    const float* __restrict__ bl, const float* __restrict__ msg,
    const float* __restrict__ cnt, float* __restrict__ out) {
  __shared__ float As[64][17];    // +1 pad
  __shared__ float Ws[16][128];
  const int t    = threadIdx.x;
  const int tc   = t & 31;        // col group 0..31
  const int tr   = t >> 5;        // row group 0..7
  const int row0 = blockIdx.x * 64;

  float acc[8][4] = {};

  for (int k0 = 0; k0 < DIM; k0 += 16) {
    // stage W tile: 16x128 = 2048 floats, 8 per thread, coalesced
#pragma unroll
    for (int i = 0; i < 8; ++i) {
      const int idx = i * 256 + t;
      Ws[idx >> 7][idx & 127] = Wr[(size_t)(k0 + (idx >> 7)) * DIM + (idx & 127)];
    }
    // stage A tile: 64x16 = 1024 floats, 4 per thread
#pragma unroll
    for (int i = 0; i < 4; ++i) {
      const int idx  = i * 256 + t;
      const int r    = idx >> 4;
      const int kk   = idx & 15;
      const int grow = row0 + r;
      As[r][kk] = (grow < N_CELL) ? xc[(size_t)grow * DIM + k0 + kk] : 0.f;
    }
    __syncthreads();
#pragma unroll
    for (int kk = 0; kk < 16; ++kk) {
      float a[8], w[4];
#pragma unroll
      for (int r = 0; r < 8; ++r) a[r] = As[tr * 8 + r][kk];
#pragma unroll
      for (int c = 0; c < 4; ++c) w[c] = Ws[kk][tc + c * 32];
#pragma unroll
      for (int r = 0; r < 8; ++r)
#pragma unroll
        for (int c = 0; c < 4; ++c)
          acc[r][c] += a[r] * w[c];
    }
    __syncthreads();
  }

  // epilogue: + msg/cnt + bias
#pragma unroll
  for (int r = 0; r < 8; ++r) {
    const int grow = row0 + tr * 8 + r;
    if (grow >= N_CELL) continue;
    const float ic = 1.0f / fmaxf(cnt[grow], 1.0f);
#pragma unroll
    for (int c = 0; c < 4; ++c) {
      const int col = tc + c * 32;
      out[(size_t)grow * DIM + col] =
          acc[r][c] + msg[(size_t)grow * DIM + col] * ic + bl[col];
    }
  }
}

// ---------------------------------------------------------------------------
// Kernel 4: per-column sum / sumsq partials -> atomics into stats[0:256]
// ---------------------------------------------------------------------------
__global__ __launch_bounds__(256) void bn_stats(
    const float* __restrict__ out, float* __restrict__ stats) {
  __shared__ float s1[2][128], s2[2][128];
  const int t  = threadIdx.x;
  const int tc = t & 127;
  const int tr = t >> 7;   // 0..1
  float a = 0.f, b = 0.f;
  for (int r = blockIdx.x * 2 + tr; r < N_CELL; r += gridDim.x * 2) {
    const float v = out[(size_t)r * DIM + tc];
    a += v;
    b += v * v;
  }
  s1[tr][tc] = a;
  s2[tr][tc] = b;
  __syncthreads();
  if (tr == 0) {
    unsafeAtomicAdd(&stats[tc],       s1[0][tc] + s1[1][tc]);
    unsafeAtomicAdd(&stats[128 + tc], s2[0][tc] + s2[1][tc]);
  }
}

// ---------------------------------------------------------------------------
// Kernel 5: finalize mu / inv_std
// ---------------------------------------------------------------------------
__global__ __launch_bounds__(128) void bn_finalize(float* __restrict__ stats) {
  const int j = threadIdx.x;
  const float mu  = stats[j] / (float)N_CELL;
  const float var = stats[128 + j] / (float)N_CELL - mu * mu;
  stats[256 + j] = mu;
  stats[384 + j] = rsqrtf(var + EPS_BN);
}

// ---------------------------------------------------------------------------
// Kernel 6: normalize in place (float4)
// ---------------------------------------------------------------------------
__global__ __launch_bounds__(256) void bn_apply(
    float* __restrict__ out, const float* __restrict__ stats) {
  const size_t total = (size_t)N_CELL * DIM / 4;
  const size_t step  = (size_t)gridDim.x * blockDim.x;
  for (size_t i = (size_t)blockIdx.x * blockDim.x + threadIdx.x; i < total;
       i += step) {
    float4 v = ((float4*)out)[i];
    const int col = (int)((i * 4) & (DIM - 1));
    v.x = (v.x - stats[256 + col + 0]) * stats[384 + col + 0];
    v.y = (v.y - stats[256 + col + 1]) * stats[384 + col + 1];
    v.z = (v.z - stats[256 + col + 2]) * stats[384 + col + 2];
    v.w = (v.w - stats[256 + col + 3]) * stats[384 + col + 3];
    ((float4*)out)[i] = v;
  }
}

// ---------------------------------------------------------------------------
extern "C" void kernel_launch(void* const* d_in, const int* in_sizes, int n_in,
                              void* d_out, int out_size, void* d_ws,
                              size_t ws_size, hipStream_t stream) {
  const float* x_cell = (const float*)d_in[0];
  const float* x_gene = (const float*)d_in[1];
  const float* Wl_gc  = (const float*)d_in[2];
  const float* bl_gc  = (const float*)d_in[3];
  const float* Wr_gc  = (const float*)d_in[4];
  // d_in[5..7] (cg weights) are dead: only last-layer `cell` is returned and
  // layers re-read the ORIGINAL x_dict, so gene branch never feeds anything.
  const int* gc_src = (const int*)d_in[8];
  const int* gc_dst = (const int*)d_in[9];
  const int  E      = in_sizes[8];

  // layer index L-1 = 1
  const float* Wl1 = Wl_gc + DIM * DIM;
  const float* bl1 = bl_gc + DIM;
  const float* Wr1 = Wr_gc + DIM * DIM;

  float* ws    = (float*)d_ws;
  float* msg   = ws + WS_MSG;
  float* cnt   = ws + WS_CNT;
  float* stats = ws + WS_STATS;
  float* ygene = ws + WS_YGENE;
  float* out   = (float*)d_out;

  // zero msg + cnt + stats (graph-capture-safe async memset)
  hipMemsetAsync(d_ws, 0, (size_t)WS_ZERO_FLOATS * sizeof(float), stream);

  ygene_gemm<<<N_GENE / 8, 128, 0, stream>>>(x_gene, Wl1, ygene);
  scatter_edges<<<2048, 256, 0, stream>>>(gc_src, gc_dst, ygene, msg, cnt, E);
  main_gemm<<<(N_CELL + 63) / 64, 256, 0, stream>>>(x_cell, Wr1, bl1, msg, cnt,
                                                    out);
  bn_stats<<<512, 256, 0, stream>>>(out, stats);
  bn_finalize<<<1, 128, 0, stream>>>(stats);
  bn_apply<<<2048, 256, 0, stream>>>(out, stats);
}

// Round 2
// 370.700 us; speedup vs baseline: 3.8385x; 3.8385x over previous
//
#include <hip/hip_runtime.h>

// Problem constants (from reference)
#define N_CELL 60000
#define N_GENE 4000
#define DIM    128
#define EPS_BN 1e-5f

// Workspace layout (4-byte units).  Zeroed region = first WS_ZERO words.
//   stats   [512]          @ 0          (sum,sumsq,mu,istd — 128 each)
//   row_ptr [N_CELL+1]     @ 512        (int; row_ptr[1+i] starts as hist[i])
//   cursor  [N_CELL]       @ 60513      (int)
//   --- end of zeroed region (120513 words) ---
//   msg     [N_CELL*DIM]   @ 120576     (aligned 256B)
//   ygene   [N_GENE*DIM]   @ 7800576
//   csr_src [E]            @ 8312576    (int)
//   bsums   [256]          @ 9812576    (int)
// total ~9.81M words = 39.3 MB
#define WS_STATS   0
#define WS_ROWPTR  512
#define WS_CURSOR  60513
#define WS_ZERO    120513
#define WS_MSG     120576
#define WS_YGENE   7800576
#define WS_CSR     8312576
#define WS_BSUMS   9812576

// ---------------------------------------------------------------------------
// Kernel 1: y_gene = x_gene @ Wl   [4000 x 128] = [4000 x 128] @ [128 x 128]
// ---------------------------------------------------------------------------
__global__ __launch_bounds__(128) void ygene_gemm(
    const float* __restrict__ xg, const float* __restrict__ Wl,
    float* __restrict__ y) {
  const int j  = threadIdx.x;
  const int r0 = blockIdx.x * 8;
  float acc[8] = {};
  for (int k = 0; k < DIM; ++k) {
    const float w = Wl[k * DIM + j];
#pragma unroll
    for (int r = 0; r < 8; ++r)
      acc[r] += xg[(size_t)(r0 + r) * DIM + k] * w;
  }
#pragma unroll
  for (int r = 0; r < 8; ++r)
    y[(size_t)(r0 + r) * DIM + j] = acc[r];
}

// ---------------------------------------------------------------------------
// CSR build step 1: histogram of dst into row_ptr[1+d] (int atomics, L2)
// ---------------------------------------------------------------------------
__global__ __launch_bounds__(256) void hist_dst(
    const int* __restrict__ dst, int* __restrict__ rp1, int E) {
  const int step = gridDim.x * blockDim.x;
  for (int i = blockIdx.x * blockDim.x + threadIdx.x; i < E; i += step)
    atomicAdd(&rp1[dst[i]], 1);
}

// ---------------------------------------------------------------------------
// CSR build step 2a: per-256-block inclusive scan of row_ptr[1..N_CELL]
// ---------------------------------------------------------------------------
__global__ __launch_bounds__(256) void scan1(
    int* __restrict__ rp1, int* __restrict__ bsums, int n) {
  __shared__ int s[256];
  const int t = threadIdx.x;
  const int i = blockIdx.x * 256 + t;
  int v = (i < n) ? rp1[i] : 0;
  s[t] = v;
  __syncthreads();
#pragma unroll
  for (int off = 1; off < 256; off <<= 1) {
    int x = (t >= off) ? s[t - off] : 0;
    __syncthreads();
    s[t] += x;
    __syncthreads();
  }
  if (i < n) rp1[i] = s[t];
  if (t == 255) bsums[blockIdx.x] = s[255];
}

// ---------------------------------------------------------------------------
// CSR build step 2b: exclusive scan of block sums (single block, nb <= 256)
// ---------------------------------------------------------------------------
__global__ __launch_bounds__(256) void scan2(int* __restrict__ bsums, int nb) {
  __shared__ int s[256];
  const int t = threadIdx.x;
  int v = (t < nb) ? bsums[t] : 0;
  s[t] = v;
  __syncthreads();
#pragma unroll
  for (int off = 1; off < 256; off <<= 1) {
    int x = (t >= off) ? s[t - off] : 0;
    __syncthreads();
    s[t] += x;
    __syncthreads();
  }
  if (t < nb) bsums[t] = s[t] - v;  // exclusive
}

// ---------------------------------------------------------------------------
// CSR build step 2c: add block offsets
// ---------------------------------------------------------------------------
__global__ __launch_bounds__(256) void scan3(
    int* __restrict__ rp1, const int* __restrict__ bsums, int n) {
  const int i = blockIdx.x * 256 + threadIdx.x;
  if (i < n) rp1[i] += bsums[blockIdx.x];
}

// ---------------------------------------------------------------------------
// CSR build step 3: fill csr_src (src indices grouped by dst)
// ---------------------------------------------------------------------------
__global__ __launch_bounds__(256) void csr_fill(
    const int* __restrict__ src, const int* __restrict__ dst,
    const int* __restrict__ rp, int* __restrict__ cursor,
    int* __restrict__ csr, int E) {
  const int step = gridDim.x * blockDim.x;
  for (int i = blockIdx.x * blockDim.x + threadIdx.x; i < E; i += step) {
    const int d   = dst[i];
    const int pos = atomicAdd(&cursor[d], 1);
    csr[rp[d] + pos] = src[i];
  }
}

// ---------------------------------------------------------------------------
// Kernel: gather-aggregate.  One wave per cell; lane holds 2 dims.
//   msg[c] = mean over edges of y_gene[csr[e]]
// y_gene (2 MB) is L2-resident -> gather traffic stays on-die.
// ---------------------------------------------------------------------------
__global__ __launch_bounds__(256) void aggregate(
    const int* __restrict__ rp, const int* __restrict__ csr,
    const float* __restrict__ y, float* __restrict__ msg) {
  const int wave = (blockIdx.x * 256 + threadIdx.x) >> 6;
  const int lane = threadIdx.x & 63;
  if (wave >= N_CELL) return;
  const int beg = rp[wave], end = rp[wave + 1];
  float ax = 0.f, ay = 0.f;
  int e = beg;
  for (; e + 1 < end; e += 2) {           // 2-wide for memory-level parallelism
    const int s0 = csr[e];
    const int s1 = csr[e + 1];
    const float2 v0 = *(const float2*)(y + (size_t)s0 * DIM + lane * 2);
    const float2 v1 = *(const float2*)(y + (size_t)s1 * DIM + lane * 2);
    ax += v0.x + v1.x;
    ay += v0.y + v1.y;
  }
  if (e < end) {
    const float2 v = *(const float2*)(y + (size_t)csr[e] * DIM + lane * 2);
    ax += v.x;
    ay += v.y;
  }
  const float ic = 1.0f / fmaxf((float)(end - beg), 1.0f);
  *(float2*)(msg + (size_t)wave * DIM + lane * 2) = make_float2(ax * ic, ay * ic);
}

// ---------------------------------------------------------------------------
// Kernel: out_pre = x_cell @ Wr + msg + bl   (msg already mean-scaled)
// ---------------------------------------------------------------------------
__global__ __launch_bounds__(256) void main_gemm(
    const float* __restrict__ xc, const float* __restrict__ Wr,
    const float* __restrict__ bl, const float* __restrict__ msg,
    float* __restrict__ out) {
  __shared__ float As[64][17];
  __shared__ float Ws[16][128];
  const int t    = threadIdx.x;
  const int tc   = t & 31;
  const int tr   = t >> 5;
  const int row0 = blockIdx.x * 64;

  float acc[8][4] = {};

  for (int k0 = 0; k0 < DIM; k0 += 16) {
#pragma unroll
    for (int i = 0; i < 8; ++i) {
      const int idx = i * 256 + t;
      Ws[idx >> 7][idx & 127] = Wr[(size_t)(k0 + (idx >> 7)) * DIM + (idx & 127)];
    }
#pragma unroll
    for (int i = 0; i < 4; ++i) {
      const int idx  = i * 256 + t;
      const int r    = idx >> 4;
      const int kk   = idx & 15;
      const int grow = row0 + r;
      As[r][kk] = (grow < N_CELL) ? xc[(size_t)grow * DIM + k0 + kk] : 0.f;
    }
    __syncthreads();
#pragma unroll
    for (int kk = 0; kk < 16; ++kk) {
      float a[8], w[4];
#pragma unroll
      for (int r = 0; r < 8; ++r) a[r] = As[tr * 8 + r][kk];
#pragma unroll
      for (int c = 0; c < 4; ++c) w[c] = Ws[kk][tc + c * 32];
#pragma unroll
      for (int r = 0; r < 8; ++r)
#pragma unroll
        for (int c = 0; c < 4; ++c)
          acc[r][c] += a[r] * w[c];
    }
    __syncthreads();
  }

#pragma unroll
  for (int r = 0; r < 8; ++r) {
    const int grow = row0 + tr * 8 + r;
    if (grow >= N_CELL) continue;
#pragma unroll
    for (int c = 0; c < 4; ++c) {
      const int col = tc + c * 32;
      out[(size_t)grow * DIM + col] =
          acc[r][c] + msg[(size_t)grow * DIM + col] + bl[col];
    }
  }
}

// ---------------------------------------------------------------------------
// BN stats: per-column sum/sumsq partials -> atomics into stats[0:256]
// ---------------------------------------------------------------------------
__global__ __launch_bounds__(256) void bn_stats(
    const float* __restrict__ out, float* __restrict__ stats) {
  __shared__ float s1[2][128], s2[2][128];
  const int t  = threadIdx.x;
  const int tc = t & 127;
  const int tr = t >> 7;
  float a = 0.f, b = 0.f;
  for (int r = blockIdx.x * 2 + tr; r < N_CELL; r += gridDim.x * 2) {
    const float v = out[(size_t)r * DIM + tc];
    a += v;
    b += v * v;
  }
  s1[tr][tc] = a;
  s2[tr][tc] = b;
  __syncthreads();
  if (tr == 0) {
    unsafeAtomicAdd(&stats[tc],       s1[0][tc] + s1[1][tc]);
    unsafeAtomicAdd(&stats[128 + tc], s2[0][tc] + s2[1][tc]);
  }
}

__global__ __launch_bounds__(128) void bn_finalize(float* __restrict__ stats) {
  const int j = threadIdx.x;
  const float mu  = stats[j] / (float)N_CELL;
  const float var = stats[128 + j] / (float)N_CELL - mu * mu;
  stats[256 + j] = mu;
  stats[384 + j] = rsqrtf(var + EPS_BN);
}

__global__ __launch_bounds__(256) void bn_apply(
    float* __restrict__ out, const float* __restrict__ stats) {
  const size_t total = (size_t)N_CELL * DIM / 4;
  const size_t step  = (size_t)gridDim.x * blockDim.x;
  for (size_t i = (size_t)blockIdx.x * blockDim.x + threadIdx.x; i < total;
       i += step) {
    float4 v = ((float4*)out)[i];
    const int col = (int)((i * 4) & (DIM - 1));
    v.x = (v.x - stats[256 + col + 0]) * stats[384 + col + 0];
    v.y = (v.y - stats[256 + col + 1]) * stats[384 + col + 1];
    v.z = (v.z - stats[256 + col + 2]) * stats[384 + col + 2];
    v.w = (v.w - stats[256 + col + 3]) * stats[384 + col + 3];
    ((float4*)out)[i] = v;
  }
}

// ---------------------------------------------------------------------------
extern "C" void kernel_launch(void* const* d_in, const int* in_sizes, int n_in,
                              void* d_out, int out_size, void* d_ws,
                              size_t ws_size, hipStream_t stream) {
  const float* x_cell = (const float*)d_in[0];
  const float* x_gene = (const float*)d_in[1];
  const float* Wl_gc  = (const float*)d_in[2];
  const float* bl_gc  = (const float*)d_in[3];
  const float* Wr_gc  = (const float*)d_in[4];
  // d_in[5..7] (cg weights) are dead: the gene branch never feeds the output.
  const int* gc_src = (const int*)d_in[8];
  const int* gc_dst = (const int*)d_in[9];
  const int  E      = in_sizes[8];

  const float* Wl1 = Wl_gc + DIM * DIM;   // layer 1 (last)
  const float* bl1 = bl_gc + DIM;
  const float* Wr1 = Wr_gc + DIM * DIM;

  float* ws    = (float*)d_ws;
  float* stats = ws + WS_STATS;
  int*   rp    = (int*)(ws + WS_ROWPTR);     // row_ptr[0..N_CELL]
  int*   cur   = (int*)(ws + WS_CURSOR);
  float* msg   = ws + WS_MSG;
  float* ygene = ws + WS_YGENE;
  int*   csr   = (int*)(ws + WS_CSR);
  int*   bsums = (int*)(ws + WS_BSUMS);
  float* out   = (float*)d_out;

  // zero stats + row_ptr + cursor (482 KB)
  hipMemsetAsync(d_ws, 0, (size_t)WS_ZERO * sizeof(float), stream);

  ygene_gemm<<<N_GENE / 8, 128, 0, stream>>>(x_gene, Wl1, ygene);

  const int NB = (N_CELL + 255) / 256;  // 235 scan blocks
  hist_dst<<<2048, 256, 0, stream>>>(gc_dst, rp + 1, E);
  scan1<<<NB, 256, 0, stream>>>(rp + 1, bsums, N_CELL);
  scan2<<<1, 256, 0, stream>>>(bsums, NB);
  scan3<<<NB, 256, 0, stream>>>(rp + 1, bsums, N_CELL);
  csr_fill<<<2048, 256, 0, stream>>>(gc_src, gc_dst, rp, cur, csr, E);

  aggregate<<<(N_CELL + 3) / 4, 256, 0, stream>>>(rp, csr, ygene, msg);
  main_gemm<<<(N_CELL + 63) / 64, 256, 0, stream>>>(x_cell, Wr1, bl1, msg, out);

  bn_stats<<<512, 256, 0, stream>>>(out, stats);
  bn_finalize<<<1, 128, 0, stream>>>(stats);
  bn_apply<<<2048, 256, 0, stream>>>(out, stats);
}

// Round 3
// 344.443 us; speedup vs baseline: 4.1311x; 1.0762x over previous
//
#include <hip/hip_runtime.h>

// Problem constants (from reference)
#define N_CELL 60000
#define N_GENE 4000
#define DIM    128
#define EPS_BN 1e-5f
#define NSLICE 8            // dst-space slices, aligned to 8 XCDs via blockIdx%8
#define SLICE_W (N_CELL / NSLICE)   // 7500

// Workspace layout (4-byte units).  Zeroed region = first WS_ZERO words.
//   stats   [512]          @ 0          (sum,sumsq,mu,istd — 128 each)
//   row_ptr [N_CELL+1]     @ 512        (int; row_ptr[1+i] starts as hist[i])
//   cursor  [N_CELL]       @ 60513      (int)
//   --- end of zeroed region (120513 words) ---
//   msg     [N_CELL*DIM]   @ 120576     (aligned 256B)
//   ygene   [N_GENE*DIM]   @ 7800576
//   csr_src [E]            @ 8312576    (int)
//   bsums   [256]          @ 9812576    (int)
// total ~9.81M words = 39.3 MB
#define WS_STATS   0
#define WS_ROWPTR  512
#define WS_CURSOR  60513
#define WS_ZERO    120513
#define WS_MSG     120576
#define WS_YGENE   7800576
#define WS_CSR     8312576
#define WS_BSUMS   9812576

// ---------------------------------------------------------------------------
// Kernel 1: y_gene = x_gene @ Wl   [4000 x 128] = [4000 x 128] @ [128 x 128]
// ---------------------------------------------------------------------------
__global__ __launch_bounds__(128) void ygene_gemm(
    const float* __restrict__ xg, const float* __restrict__ Wl,
    float* __restrict__ y) {
  const int j  = threadIdx.x;
  const int r0 = blockIdx.x * 8;
  float acc[8] = {};
  for (int k = 0; k < DIM; ++k) {
    const float w = Wl[k * DIM + j];
#pragma unroll
    for (int r = 0; r < 8; ++r)
      acc[r] += xg[(size_t)(r0 + r) * DIM + k] * w;
  }
#pragma unroll
  for (int r = 0; r < 8; ++r)
    y[(size_t)(r0 + r) * DIM + j] = acc[r];
}

// ---------------------------------------------------------------------------
// CSR build step 1: histogram of dst into row_ptr[1+d] (int atomics, L2)
// ---------------------------------------------------------------------------
__global__ __launch_bounds__(256) void hist_dst(
    const int* __restrict__ dst, int* __restrict__ rp1, int E) {
  const int step = gridDim.x * blockDim.x;
  for (int i = blockIdx.x * blockDim.x + threadIdx.x; i < E; i += step)
    atomicAdd(&rp1[dst[i]], 1);
}

// ---------------------------------------------------------------------------
// CSR build step 2a: per-256-block inclusive scan of row_ptr[1..N_CELL]
// ---------------------------------------------------------------------------
__global__ __launch_bounds__(256) void scan1(
    int* __restrict__ rp1, int* __restrict__ bsums, int n) {
  __shared__ int s[256];
  const int t = threadIdx.x;
  const int i = blockIdx.x * 256 + t;
  int v = (i < n) ? rp1[i] : 0;
  s[t] = v;
  __syncthreads();
#pragma unroll
  for (int off = 1; off < 256; off <<= 1) {
    int x = (t >= off) ? s[t - off] : 0;
    __syncthreads();
    s[t] += x;
    __syncthreads();
  }
  if (i < n) rp1[i] = s[t];
  if (t == 255) bsums[blockIdx.x] = s[255];
}

// ---------------------------------------------------------------------------
// CSR build step 2b: exclusive scan of block sums (single block, nb <= 256)
// ---------------------------------------------------------------------------
__global__ __launch_bounds__(256) void scan2(int* __restrict__ bsums, int nb) {
  __shared__ int s[256];
  const int t = threadIdx.x;
  int v = (t < nb) ? bsums[t] : 0;
  s[t] = v;
  __syncthreads();
#pragma unroll
  for (int off = 1; off < 256; off <<= 1) {
    int x = (t >= off) ? s[t - off] : 0;
    __syncthreads();
    s[t] += x;
    __syncthreads();
  }
  if (t < nb) bsums[t] = s[t] - v;  // exclusive
}

// ---------------------------------------------------------------------------
// CSR build step 2c: add block offsets
// ---------------------------------------------------------------------------
__global__ __launch_bounds__(256) void scan3(
    int* __restrict__ rp1, const int* __restrict__ bsums, int n) {
  const int i = blockIdx.x * 256 + threadIdx.x;
  if (i < n) rp1[i] += bsums[blockIdx.x];
}

// ---------------------------------------------------------------------------
// CSR build step 3: fill csr_src, XCD-SLICED.
// Slice s = blockIdx%8 (HW round-robins consecutive blocks across the 8
// XCDs) owns dst in [s*7500, (s+1)*7500).  Each csr line is then written by
// ONE XCD only -> lines fill completely in that L2 before writeback ->
// WRITE_SIZE drops from ~64 B/edge to ~4 B/edge.  Each slice grid-strides
// the full edge list; re-reads are L3-served.
// ---------------------------------------------------------------------------
__global__ __launch_bounds__(256) void csr_fill_sliced(
    const int* __restrict__ src, const int* __restrict__ dst,
    const int* __restrict__ rp, int* __restrict__ cursor,
    int* __restrict__ csr, int E) {
  const int slice = blockIdx.x & (NSLICE - 1);
  const int lo    = slice * SLICE_W;
  const int bidx  = blockIdx.x >> 3;          // block index within slice
  const int bper  = gridDim.x >> 3;           // blocks per slice
  const int step  = bper * 256;
  for (int i = bidx * 256 + threadIdx.x; i < E; i += step) {
    const int d = dst[i];
    if ((unsigned)(d - lo) >= (unsigned)SLICE_W) continue;
    const int pos = atomicAdd(&cursor[d], 1);
    csr[rp[d] + pos] = src[i];
  }
}

// ---------------------------------------------------------------------------
// Kernel: gather-aggregate.  One wave per cell; lane holds 2 dims.
//   msg[c] = mean over edges of y_gene[csr[e]]
// y_gene (2 MB) is L2-resident -> gather traffic stays on-die.
// ---------------------------------------------------------------------------
__global__ __launch_bounds__(256) void aggregate(
    const int* __restrict__ rp, const int* __restrict__ csr,
    const float* __restrict__ y, float* __restrict__ msg) {
  const int wave = (blockIdx.x * 256 + threadIdx.x) >> 6;
  const int lane = threadIdx.x & 63;
  if (wave >= N_CELL) return;
  const int beg = rp[wave], end = rp[wave + 1];
  float ax = 0.f, ay = 0.f;
  int e = beg;
  for (; e + 1 < end; e += 2) {           // 2-wide for memory-level parallelism
    const int s0 = csr[e];
    const int s1 = csr[e + 1];
    const float2 v0 = *(const float2*)(y + (size_t)s0 * DIM + lane * 2);
    const float2 v1 = *(const float2*)(y + (size_t)s1 * DIM + lane * 2);
    ax += v0.x + v1.x;
    ay += v0.y + v1.y;
  }
  if (e < end) {
    const float2 v = *(const float2*)(y + (size_t)csr[e] * DIM + lane * 2);
    ax += v.x;
    ay += v.y;
  }
  const float ic = 1.0f / fmaxf((float)(end - beg), 1.0f);
  *(float2*)(msg + (size_t)wave * DIM + lane * 2) = make_float2(ax * ic, ay * ic);
}

// ---------------------------------------------------------------------------
// Kernel: out_pre = x_cell @ Wr + msg + bl   (msg already mean-scaled)
// ---------------------------------------------------------------------------
__global__ __launch_bounds__(256) void main_gemm(
    const float* __restrict__ xc, const float* __restrict__ Wr,
    const float* __restrict__ bl, const float* __restrict__ msg,
    float* __restrict__ out) {
  __shared__ float As[64][17];
  __shared__ float Ws[16][128];
  const int t    = threadIdx.x;
  const int tc   = t & 31;
  const int tr   = t >> 5;
  const int row0 = blockIdx.x * 64;

  float acc[8][4] = {};

  for (int k0 = 0; k0 < DIM; k0 += 16) {
#pragma unroll
    for (int i = 0; i < 8; ++i) {
      const int idx = i * 256 + t;
      Ws[idx >> 7][idx & 127] = Wr[(size_t)(k0 + (idx >> 7)) * DIM + (idx & 127)];
    }
#pragma unroll
    for (int i = 0; i < 4; ++i) {
      const int idx  = i * 256 + t;
      const int r    = idx >> 4;
      const int kk   = idx & 15;
      const int grow = row0 + r;
      As[r][kk] = (grow < N_CELL) ? xc[(size_t)grow * DIM + k0 + kk] : 0.f;
    }
    __syncthreads();
#pragma unroll
    for (int kk = 0; kk < 16; ++kk) {
      float a[8], w[4];
#pragma unroll
      for (int r = 0; r < 8; ++r) a[r] = As[tr * 8 + r][kk];
#pragma unroll
      for (int c = 0; c < 4; ++c) w[c] = Ws[kk][tc + c * 32];
#pragma unroll
      for (int r = 0; r < 8; ++r)
#pragma unroll
        for (int c = 0; c < 4; ++c)
          acc[r][c] += a[r] * w[c];
    }
    __syncthreads();
  }

#pragma unroll
  for (int r = 0; r < 8; ++r) {
    const int grow = row0 + tr * 8 + r;
    if (grow >= N_CELL) continue;
#pragma unroll
    for (int c = 0; c < 4; ++c) {
      const int col = tc + c * 32;
      out[(size_t)grow * DIM + col] =
          acc[r][c] + msg[(size_t)grow * DIM + col] + bl[col];
    }
  }
}

// ---------------------------------------------------------------------------
// BN stats: per-column sum/sumsq partials -> atomics into stats[0:256]
// ---------------------------------------------------------------------------
__global__ __launch_bounds__(256) void bn_stats(
    const float* __restrict__ out, float* __restrict__ stats) {
  __shared__ float s1[2][128], s2[2][128];
  const int t  = threadIdx.x;
  const int tc = t & 127;
  const int tr = t >> 7;
  float a = 0.f, b = 0.f;
  for (int r = blockIdx.x * 2 + tr; r < N_CELL; r += gridDim.x * 2) {
    const float v = out[(size_t)r * DIM + tc];
    a += v;
    b += v * v;
  }
  s1[tr][tc] = a;
  s2[tr][tc] = b;
  __syncthreads();
  if (tr == 0) {
    unsafeAtomicAdd(&stats[tc],       s1[0][tc] + s1[1][tc]);
    unsafeAtomicAdd(&stats[128 + tc], s2[0][tc] + s2[1][tc]);
  }
}

__global__ __launch_bounds__(128) void bn_finalize(float* __restrict__ stats) {
  const int j = threadIdx.x;
  const float mu  = stats[j] / (float)N_CELL;
  const float var = stats[128 + j] / (float)N_CELL - mu * mu;
  stats[256 + j] = mu;
  stats[384 + j] = rsqrtf(var + EPS_BN);
}

__global__ __launch_bounds__(256) void bn_apply(
    float* __restrict__ out, const float* __restrict__ stats) {
  const size_t total = (size_t)N_CELL * DIM / 4;
  const size_t step  = (size_t)gridDim.x * blockDim.x;
  for (size_t i = (size_t)blockIdx.x * blockDim.x + threadIdx.x; i < total;
       i += step) {
    float4 v = ((float4*)out)[i];
    const int col = (int)((i * 4) & (DIM - 1));
    v.x = (v.x - stats[256 + col + 0]) * stats[384 + col + 0];
    v.y = (v.y - stats[256 + col + 1]) * stats[384 + col + 1];
    v.z = (v.z - stats[256 + col + 2]) * stats[384 + col + 2];
    v.w = (v.w - stats[256 + col + 3]) * stats[384 + col + 3];
    ((float4*)out)[i] = v;
  }
}

// ---------------------------------------------------------------------------
extern "C" void kernel_launch(void* const* d_in, const int* in_sizes, int n_in,
                              void* d_out, int out_size, void* d_ws,
                              size_t ws_size, hipStream_t stream) {
  const float* x_cell = (const float*)d_in[0];
  const float* x_gene = (const float*)d_in[1];
  const float* Wl_gc  = (const float*)d_in[2];
  const float* bl_gc  = (const float*)d_in[3];
  const float* Wr_gc  = (const float*)d_in[4];
  // d_in[5..7] (cg weights) are dead: the gene branch never feeds the output.
  const int* gc_src = (const int*)d_in[8];
  const int* gc_dst = (const int*)d_in[9];
  const int  E      = in_sizes[8];

  const float* Wl1 = Wl_gc + DIM * DIM;   // layer 1 (last)
  const float* bl1 = bl_gc + DIM;
  const float* Wr1 = Wr_gc + DIM * DIM;

  float* ws    = (float*)d_ws;
  float* stats = ws + WS_STATS;
  int*   rp    = (int*)(ws + WS_ROWPTR);     // row_ptr[0..N_CELL]
  int*   cur   = (int*)(ws + WS_CURSOR);
  float* msg   = ws + WS_MSG;
  float* ygene = ws + WS_YGENE;
  int*   csr   = (int*)(ws + WS_CSR);
  int*   bsums = (int*)(ws + WS_BSUMS);
  float* out   = (float*)d_out;

  // zero stats + row_ptr + cursor (482 KB)
  hipMemsetAsync(d_ws, 0, (size_t)WS_ZERO * sizeof(float), stream);

  ygene_gemm<<<N_GENE / 8, 128, 0, stream>>>(x_gene, Wl1, ygene);

  const int NB = (N_CELL + 255) / 256;  // 235 scan blocks
  hist_dst<<<2048, 256, 0, stream>>>(gc_dst, rp + 1, E);
  scan1<<<NB, 256, 0, stream>>>(rp + 1, bsums, N_CELL);
  scan2<<<1, 256, 0, stream>>>(bsums, NB);
  scan3<<<NB, 256, 0, stream>>>(rp + 1, bsums, N_CELL);
  csr_fill_sliced<<<2048, 256, 0, stream>>>(gc_src, gc_dst, rp, cur, csr, E);

  aggregate<<<(N_CELL + 3) / 4, 256, 0, stream>>>(rp, csr, ygene, msg);
  main_gemm<<<(N_CELL + 63) / 64, 256, 0, stream>>>(x_cell, Wr1, bl1, msg, out);

  bn_stats<<<512, 256, 0, stream>>>(out, stats);
  bn_finalize<<<1, 128, 0, stream>>>(stats);
  bn_apply<<<2048, 256, 0, stream>>>(out, stats);
}

// Round 4
// 303.244 us; speedup vs baseline: 4.6924x; 1.1359x over previous
//
#include <hip/hip_runtime.h>

// Problem constants (from reference)
#define N_CELL 60000
#define N_GENE 4000
#define DIM    128
#define EPS_BN 1e-5f
#define NSLICE 8            // dst-space slices, aligned to 8 XCDs via blockIdx%8
#define SLICE_W (N_CELL / NSLICE)   // 7500

// Workspace layout (4-byte units).  Zeroed region = first WS_ZERO words.
//   stats   [512]          @ 0          (sum,sumsq,mu,istd — 128 each)
//   row_ptr [N_CELL+1]     @ 512        (int; row_ptr[1+i] starts as hist[i])
//   cursor  [N_CELL]       @ 60513      (int)
//   --- end of zeroed region (120513 words) ---
//   msg     [N_CELL*DIM]   @ 120576
//   ygene   [N_GENE*DIM]   @ 7800576
//   csr_src [E]            @ 8312576    (int)
//   bsums   [256]          @ 9812576    (int)
//   Wb      [16384 bf16]   @ 9812832    (fragment-ordered bf16 Wr, 32 KB)
// total ~9.82M words = 39.3 MB
#define WS_STATS   0
#define WS_ROWPTR  512
#define WS_CURSOR  60513
#define WS_ZERO    120513
#define WS_MSG     120576
#define WS_YGENE   7800576
#define WS_CSR     8312576
#define WS_BSUMS   9812576
#define WS_WB      9812832

typedef __bf16 bf16x8 __attribute__((ext_vector_type(8)));
typedef float  f32x4  __attribute__((ext_vector_type(4)));

// ---------------------------------------------------------------------------
// Kernel 1: y_gene = x_gene @ Wl (fp32 — small, keeps aggregate path exact)
// ---------------------------------------------------------------------------
__global__ __launch_bounds__(128) void ygene_gemm(
    const float* __restrict__ xg, const float* __restrict__ Wl,
    float* __restrict__ y) {
  const int j  = threadIdx.x;
  const int r0 = blockIdx.x * 8;
  float acc[8] = {};
  for (int k = 0; k < DIM; ++k) {
    const float w = Wl[k * DIM + j];
#pragma unroll
    for (int r = 0; r < 8; ++r)
      acc[r] += xg[(size_t)(r0 + r) * DIM + k] * w;
  }
#pragma unroll
  for (int r = 0; r < 8; ++r)
    y[(size_t)(r0 + r) * DIM + j] = acc[r];
}

// ---------------------------------------------------------------------------
// conv_w: Wr fp32 [128k][128j] -> fragment-ordered bf16 for 16x16x32 MFMA.
// Fragment address: chunk=(k>>5)*8+(j>>4), lane=((k>>3)&3)*16+(j&15), e=k&7.
// Lane l of chunk then reads its 8 bf16 contiguously at (chunk*64+l)*16 B.
// ---------------------------------------------------------------------------
__global__ __launch_bounds__(256) void conv_w(
    const float* __restrict__ w, unsigned short* __restrict__ wb) {
  const int i = blockIdx.x * 256 + threadIdx.x;  // 0..16383
  const int k = i >> 7, j = i & 127;
  const int chunk = (k >> 5) * 8 + (j >> 4);
  const int lane  = ((k >> 3) & 3) * 16 + (j & 15);
  const int e     = k & 7;
  const __bf16 b  = (__bf16)w[i];
  wb[(chunk * 64 + lane) * 8 + e] = __builtin_bit_cast(unsigned short, b);
}

// ---------------------------------------------------------------------------
// CSR build step 1: histogram of dst into row_ptr[1+d]
// ---------------------------------------------------------------------------
__global__ __launch_bounds__(256) void hist_dst(
    const int* __restrict__ dst, int* __restrict__ rp1, int E) {
  const int step = gridDim.x * blockDim.x;
  for (int i = blockIdx.x * blockDim.x + threadIdx.x; i < E; i += step)
    atomicAdd(&rp1[dst[i]], 1);
}

__global__ __launch_bounds__(256) void scan1(
    int* __restrict__ rp1, int* __restrict__ bsums, int n) {
  __shared__ int s[256];
  const int t = threadIdx.x;
  const int i = blockIdx.x * 256 + t;
  int v = (i < n) ? rp1[i] : 0;
  s[t] = v;
  __syncthreads();
#pragma unroll
  for (int off = 1; off < 256; off <<= 1) {
    int x = (t >= off) ? s[t - off] : 0;
    __syncthreads();
    s[t] += x;
    __syncthreads();
  }
  if (i < n) rp1[i] = s[t];
  if (t == 255) bsums[blockIdx.x] = s[255];
}

__global__ __launch_bounds__(256) void scan2(int* __restrict__ bsums, int nb) {
  __shared__ int s[256];
  const int t = threadIdx.x;
  int v = (t < nb) ? bsums[t] : 0;
  s[t] = v;
  __syncthreads();
#pragma unroll
  for (int off = 1; off < 256; off <<= 1) {
    int x = (t >= off) ? s[t - off] : 0;
    __syncthreads();
    s[t] += x;
    __syncthreads();
  }
  if (t < nb) bsums[t] = s[t] - v;  // exclusive
}

__global__ __launch_bounds__(256) void scan3(
    int* __restrict__ rp1, const int* __restrict__ bsums, int n) {
  const int i = blockIdx.x * 256 + threadIdx.x;
  if (i < n) rp1[i] += bsums[blockIdx.x];
}

// ---------------------------------------------------------------------------
// CSR build step 3: fill csr_src, XCD-sliced (see R3 notes)
// ---------------------------------------------------------------------------
__global__ __launch_bounds__(256) void csr_fill_sliced(
    const int* __restrict__ src, const int* __restrict__ dst,
    const int* __restrict__ rp, int* __restrict__ cursor,
    int* __restrict__ csr, int E) {
  const int slice = blockIdx.x & (NSLICE - 1);
  const int lo    = slice * SLICE_W;
  const int bidx  = blockIdx.x >> 3;
  const int bper  = gridDim.x >> 3;
  const int step  = bper * 256;
  for (int i = bidx * 256 + threadIdx.x; i < E; i += step) {
    const int d = dst[i];
    if ((unsigned)(d - lo) >= (unsigned)SLICE_W) continue;
    const int pos = atomicAdd(&cursor[d], 1);
    csr[rp[d] + pos] = src[i];
  }
}

// ---------------------------------------------------------------------------
// gather-aggregate: msg[c] = mean over edges of y_gene[csr[e]]  (fp32)
// ---------------------------------------------------------------------------
__global__ __launch_bounds__(256) void aggregate(
    const int* __restrict__ rp, const int* __restrict__ csr,
    const float* __restrict__ y, float* __restrict__ msg) {
  const int wave = (blockIdx.x * 256 + threadIdx.x) >> 6;
  const int lane = threadIdx.x & 63;
  if (wave >= N_CELL) return;
  const int beg = rp[wave], end = rp[wave + 1];
  float ax = 0.f, ay = 0.f;
  int e = beg;
  for (; e + 1 < end; e += 2) {
    const int s0 = csr[e];
    const int s1 = csr[e + 1];
    const float2 v0 = *(const float2*)(y + (size_t)s0 * DIM + lane * 2);
    const float2 v1 = *(const float2*)(y + (size_t)s1 * DIM + lane * 2);
    ax += v0.x + v1.x;
    ay += v0.y + v1.y;
  }
  if (e < end) {
    const float2 v = *(const float2*)(y + (size_t)csr[e] * DIM + lane * 2);
    ax += v.x;
    ay += v.y;
  }
  const float ic = 1.0f / fmaxf((float)(end - beg), 1.0f);
  *(float2*)(msg + (size_t)wave * DIM + lane * 2) = make_float2(ax * ic, ay * ic);
}

// ---------------------------------------------------------------------------
// main GEMM on matrix cores: out_pre = bf16(x_cell) @ bf16(Wr) + msg + bl
// 128x128 tile, 4 waves (2x2), K=128 staged once. A in LDS (bf16,
// XOR-swizzled 16B slots: slot ^= row&15 -> ds_read_b128 ~2-way = free).
// B frags read straight from fragment-ordered Wb in global (L1/L2-hit).
// C/D mapping (m89-verified): col = lane&15, row = (lane>>4)*4 + reg.
// ---------------------------------------------------------------------------
__global__ __launch_bounds__(256) void main_gemm_mfma(
    const float* __restrict__ xc, const unsigned short* __restrict__ wb,
    const float* __restrict__ bl, const float* __restrict__ msg,
    float* __restrict__ out) {
  __shared__ unsigned short a_lds[128 * 128];  // 32 KB
  const int t    = threadIdx.x;
  const int row0 = blockIdx.x * 128;

  // ---- stage A: fp32 -> bf16, swizzled ----
  {
    const int row  = t >> 1;
    const int h    = t & 1;
    const int grow = row0 + row;
    const bool ok  = grow < N_CELL;
    const float* xrow = xc + (size_t)grow * DIM;
#pragma unroll
    for (int i = 0; i < 4; ++i) {
      const int kk = h * 64 + i * 16;
      float4 f0, f1, f2, f3;
      if (ok) {
        f0 = *(const float4*)(xrow + kk);
        f1 = *(const float4*)(xrow + kk + 4);
        f2 = *(const float4*)(xrow + kk + 8);
        f3 = *(const float4*)(xrow + kk + 12);
      } else {
        f0 = f1 = f2 = f3 = make_float4(0.f, 0.f, 0.f, 0.f);
      }
      const float fv[16] = {f0.x, f0.y, f0.z, f0.w, f1.x, f1.y, f1.z, f1.w,
                            f2.x, f2.y, f2.z, f2.w, f3.x, f3.y, f3.z, f3.w};
      union { unsigned short u[16]; uint4 q[2]; } pk;
#pragma unroll
      for (int e = 0; e < 16; ++e) {
        const __bf16 b = (__bf16)fv[e];
        pk.u[e] = __builtin_bit_cast(unsigned short, b);
      }
      const int s0 = ((kk >> 3) + 0) ^ (row & 15);
      const int s1 = ((kk >> 3) + 1) ^ (row & 15);
      *(uint4*)&a_lds[row * 128 + s0 * 8] = pk.q[0];
      *(uint4*)&a_lds[row * 128 + s1 * 8] = pk.q[1];
    }
  }
  __syncthreads();

  const int w   = t >> 6, l = t & 63;
  const int wr  = w >> 1, wc = w & 1;
  const int l15 = l & 15, lq = l >> 4;

  f32x4 acc[4][4];
#pragma unroll
  for (int g = 0; g < 4; ++g)
#pragma unroll
    for (int c = 0; c < 4; ++c) acc[g][c] = (f32x4){0.f, 0.f, 0.f, 0.f};

#pragma unroll
  for (int ks = 0; ks < 4; ++ks) {
    bf16x8 bfr[4];
#pragma unroll
    for (int c = 0; c < 4; ++c)
      bfr[c] = *(const bf16x8*)(wb +
                (size_t)(((ks * 8 + wc * 4 + c) * 64 + l) * 8));
    bf16x8 afr[4];
#pragma unroll
    for (int g = 0; g < 4; ++g) {
      const int row = wr * 64 + g * 16 + l15;   // row & 15 == l15
      const int s   = (ks * 4 + lq) ^ l15;
      afr[g] = *(const bf16x8*)&a_lds[row * 128 + s * 8];
    }
#pragma unroll
    for (int g = 0; g < 4; ++g)
#pragma unroll
      for (int c = 0; c < 4; ++c)
        acc[g][c] = __builtin_amdgcn_mfma_f32_16x16x32_bf16(
            afr[g], bfr[c], acc[g][c], 0, 0, 0);
  }

  // epilogue: + msg + bias (fp32)
#pragma unroll
  for (int g = 0; g < 4; ++g) {
#pragma unroll
    for (int c = 0; c < 4; ++c) {
      const int col = wc * 64 + c * 16 + l15;
      const float b = bl[col];
#pragma unroll
      for (int r = 0; r < 4; ++r) {
        const int grow = row0 + wr * 64 + g * 16 + lq * 4 + r;
        if (grow < N_CELL)
          out[(size_t)grow * DIM + col] =
              acc[g][c][r] + msg[(size_t)grow * DIM + col] + b;
      }
    }
  }
}

// ---------------------------------------------------------------------------
// BN stats / finalize / apply (unchanged)
// ---------------------------------------------------------------------------
__global__ __launch_bounds__(256) void bn_stats(
    const float* __restrict__ out, float* __restrict__ stats) {
  __shared__ float s1[2][128], s2[2][128];
  const int t  = threadIdx.x;
  const int tc = t & 127;
  const int tr = t >> 7;
  float a = 0.f, b = 0.f;
  for (int r = blockIdx.x * 2 + tr; r < N_CELL; r += gridDim.x * 2) {
    const float v = out[(size_t)r * DIM + tc];
    a += v;
    b += v * v;
  }
  s1[tr][tc] = a;
  s2[tr][tc] = b;
  __syncthreads();
  if (tr == 0) {
    unsafeAtomicAdd(&stats[tc],       s1[0][tc] + s1[1][tc]);
    unsafeAtomicAdd(&stats[128 + tc], s2[0][tc] + s2[1][tc]);
  }
}

__global__ __launch_bounds__(128) void bn_finalize(float* __restrict__ stats) {
  const int j = threadIdx.x;
  const float mu  = stats[j] / (float)N_CELL;
  const float var = stats[128 + j] / (float)N_CELL - mu * mu;
  stats[256 + j] = mu;
  stats[384 + j] = rsqrtf(var + EPS_BN);
}

__global__ __launch_bounds__(256) void bn_apply(
    float* __restrict__ out, const float* __restrict__ stats) {
  const size_t total = (size_t)N_CELL * DIM / 4;
  const size_t step  = (size_t)gridDim.x * blockDim.x;
  for (size_t i = (size_t)blockIdx.x * blockDim.x + threadIdx.x; i < total;
       i += step) {
    float4 v = ((float4*)out)[i];
    const int col = (int)((i * 4) & (DIM - 1));
    v.x = (v.x - stats[256 + col + 0]) * stats[384 + col + 0];
    v.y = (v.y - stats[256 + col + 1]) * stats[384 + col + 1];
    v.z = (v.z - stats[256 + col + 2]) * stats[384 + col + 2];
    v.w = (v.w - stats[256 + col + 3]) * stats[384 + col + 3];
    ((float4*)out)[i] = v;
  }
}

// ---------------------------------------------------------------------------
extern "C" void kernel_launch(void* const* d_in, const int* in_sizes, int n_in,
                              void* d_out, int out_size, void* d_ws,
                              size_t ws_size, hipStream_t stream) {
  const float* x_cell = (const float*)d_in[0];
  const float* x_gene = (const float*)d_in[1];
  const float* Wl_gc  = (const float*)d_in[2];
  const float* bl_gc  = (const float*)d_in[3];
  const float* Wr_gc  = (const float*)d_in[4];
  // d_in[5..7] (cg weights) are dead: the gene branch never feeds the output.
  const int* gc_src = (const int*)d_in[8];
  const int* gc_dst = (const int*)d_in[9];
  const int  E      = in_sizes[8];

  const float* Wl1 = Wl_gc + DIM * DIM;   // layer 1 (last)
  const float* bl1 = bl_gc + DIM;
  const float* Wr1 = Wr_gc + DIM * DIM;

  float* ws    = (float*)d_ws;
  float* stats = ws + WS_STATS;
  int*   rp    = (int*)(ws + WS_ROWPTR);
  int*   cur   = (int*)(ws + WS_CURSOR);
  float* msg   = ws + WS_MSG;
  float* ygene = ws + WS_YGENE;
  int*   csr   = (int*)(ws + WS_CSR);
  int*   bsums = (int*)(ws + WS_BSUMS);
  unsigned short* Wb = (unsigned short*)(ws + WS_WB);
  float* out   = (float*)d_out;

  hipMemsetAsync(d_ws, 0, (size_t)WS_ZERO * sizeof(float), stream);

  conv_w<<<64, 256, 0, stream>>>(Wr1, Wb);
  ygene_gemm<<<N_GENE / 8, 128, 0, stream>>>(x_gene, Wl1, ygene);

  const int NB = (N_CELL + 255) / 256;
  hist_dst<<<2048, 256, 0, stream>>>(gc_dst, rp + 1, E);
  scan1<<<NB, 256, 0, stream>>>(rp + 1, bsums, N_CELL);
  scan2<<<1, 256, 0, stream>>>(bsums, NB);
  scan3<<<NB, 256, 0, stream>>>(rp + 1, bsums, N_CELL);
  csr_fill_sliced<<<2048, 256, 0, stream>>>(gc_src, gc_dst, rp, cur, csr, E);

  aggregate<<<(N_CELL + 3) / 4, 256, 0, stream>>>(rp, csr, ygene, msg);
  main_gemm_mfma<<<(N_CELL + 127) / 128, 256, 0, stream>>>(x_cell, Wb, bl1,
                                                           msg, out);

  bn_stats<<<512, 256, 0, stream>>>(out, stats);
  bn_finalize<<<1, 128, 0, stream>>>(stats);
  bn_apply<<<2048, 256, 0, stream>>>(out, stats);
}